// Round 7
// baseline (626.229 us; speedup 1.0000x reference)
//
#include <hip/hip_runtime.h>
#include <hip/hip_bf16.h>

#define DEV __device__ __forceinline__

typedef __attribute__((ext_vector_type(8))) short short8;   // 8 x bf16 (4 VGPRs)
typedef __attribute__((ext_vector_type(4))) float f32x4;

DEV f32x4 mfma16(short8 a, short8 b, f32x4 c) {
  return __builtin_amdgcn_mfma_f32_16x16x32_bf16(a, b, c, 0, 0, 0);
}

DEV unsigned short f2bf(float f) {
  union { float f; unsigned u; } x; x.f = f;
  unsigned r = x.u + 0x7fffu + ((x.u >> 16) & 1u);   // RNE
  return (unsigned short)(r >> 16);
}

// ---------------------------------------------------------------- conversions
__global__ __launch_bounds__(256) void cvt_bf16(const float* __restrict__ in,
                                                unsigned short* __restrict__ out,
                                                int n4) {
  int i = blockIdx.x * 256 + threadIdx.x;
  if (i >= n4) return;
  float4 v = ((const float4*)in)[i];
  ushort4 o;
  o.x = f2bf(v.x); o.y = f2bf(v.y); o.z = f2bf(v.z); o.w = f2bf(v.w);
  ((ushort4*)out)[i] = o;
}

// W [K][N] f32 -> Wt [N][K] bf16  (block (32,8), grid (N/32, K/32))
__global__ __launch_bounds__(256) void cvtT(const float* __restrict__ W,
                                            unsigned short* __restrict__ Wt,
                                            int K, int N) {
  __shared__ float t[32][33];
  int n0 = blockIdx.x * 32, k0 = blockIdx.y * 32;
  int tx = threadIdx.x, ty = threadIdx.y;
#pragma unroll
  for (int i = 0; i < 4; i++)
    t[ty * 4 + i][tx] = W[(size_t)(k0 + ty * 4 + i) * N + n0 + tx];
  __syncthreads();
#pragma unroll
  for (int i = 0; i < 4; i++)
    Wt[(size_t)(n0 + ty * 4 + i) * K + k0 + tx] = f2bf(t[tx][ty * 4 + i]);
}

// ---------------------------------------------------------------- GEMM (m97 structure)
// C[M,N] = A[M,K] (bf16 rm) * Bt[N,K]^T (bf16) + bias, epilogue per MODE.
enum { M_QKV = 0, M_RES = 3, M_RELU = 4, M_F32 = 5 };

template <int MODE>
__global__ __launch_bounds__(256, 2)
void gemm_bt(const unsigned short* __restrict__ A,
             const unsigned short* __restrict__ Bt,
             const float* __restrict__ bias,
             const float* __restrict__ bias2,
             const float* __restrict__ bias3,
             const float* __restrict__ res,
             void* __restrict__ outp, int M, int N, int K) {
  __shared__ unsigned short lA[128 * 64];
  __shared__ unsigned short lB[128 * 64];
  const int tid = threadIdx.x;
  const int l = tid & 63, w = tid >> 6;
  const int wr = w >> 1, wc = w & 1;          // 2x2 wave grid, 64x64 per wave
  const int lr = l & 15, lg = l >> 4;
  // Bijective chunked XCD swizzle (T1): nwg % 8 == 0 on all our launches.
  const int lin = blockIdx.y * gridDim.x + blockIdx.x;
  const int cpx = (gridDim.x * gridDim.y) >> 3;
  const int swz = (lin & 7) * cpx + (lin >> 3);
  const int m0 = (swz % gridDim.x) * 128, n0 = (swz / gridDim.x) * 128;
  f32x4 acc[4][4] = {};

  for (int k0 = 0; k0 < K; k0 += 64) {
    __syncthreads();
#pragma unroll
    for (int i = 0; i < 4; i++) {             // A tile 128x64: 4 x 256thr x 16B
      int off = (i * 256 + tid) * 8;
      int r = off >> 6, c = off & 63;
      __builtin_amdgcn_global_load_lds(
          (const __attribute__((address_space(1))) unsigned int*)(A + (size_t)(m0 + r) * K + k0 + c),
          (__attribute__((address_space(3))) unsigned int*)(lA + off), 16, 0, 0);
    }
#pragma unroll
    for (int i = 0; i < 4; i++) {             // B^T tile 128x64
      int off = (i * 256 + tid) * 8;
      int r = off >> 6, c = off & 63;
      __builtin_amdgcn_global_load_lds(
          (const __attribute__((address_space(1))) unsigned int*)(Bt + (size_t)(n0 + r) * K + k0 + c),
          (__attribute__((address_space(3))) unsigned int*)(lB + off), 16, 0, 0);
    }
    __syncthreads();
#pragma unroll
    for (int kk = 0; kk < 2; kk++) {
      short8 af[4], bfr[4];
#pragma unroll
      for (int mt = 0; mt < 4; mt++)
        af[mt] = *(const short8*)(lA + (wr * 64 + mt * 16 + lr) * 64 + kk * 32 + lg * 8);
#pragma unroll
      for (int nt = 0; nt < 4; nt++)
        bfr[nt] = *(const short8*)(lB + (wc * 64 + nt * 16 + lr) * 64 + kk * 32 + lg * 8);
#pragma unroll
      for (int mt = 0; mt < 4; mt++)
#pragma unroll
        for (int nt = 0; nt < 4; nt++)
          acc[mt][nt] = mfma16(af[mt], bfr[nt], acc[mt][nt]);
    }
  }

  // block-uniform section for M_QKV (128-tile never straddles a 1024 boundary)
  const int sect = n0 >> 10;
  const float* bp = bias;
  if constexpr (MODE == M_QKV) bp = sect == 0 ? bias : (sect == 1 ? bias2 : bias3);

  // epilogue: C/D layout row=(lane>>4)*4+reg, col=lane&15 (verified m89/m91)
#pragma unroll
  for (int mt = 0; mt < 4; mt++) {
#pragma unroll
    for (int nt = 0; nt < 4; nt++) {
#pragma unroll
      for (int r = 0; r < 4; r++) {
        int row = m0 + wr * 64 + mt * 16 + lg * 4 + r;
        int col = n0 + wc * 64 + nt * 16 + lr;
        if constexpr (MODE == M_QKV) {
          int c10 = col & 1023;
          float v = acc[mt][nt][r] + bp[c10];
          int b = row >> 11, s = row & 2047;
          int h = c10 >> 6, dh = c10 & 63;
          unsigned short* o = (unsigned short*)outp;
          if (sect == 2) {                    // Vt[b][h][dh][s]
            o[(size_t)2 * 8388608 + ((size_t)(b * 16 + h) * 64 + dh) * 2048 + s] = f2bf(v);
          } else {                            // Q (scaled) / K : [b][h][s][dh]
            float sc = sect == 0 ? 0.125f : 1.f;
            o[(size_t)sect * 8388608 + (((size_t)(b * 16 + h) * 2048 + s) << 6) + dh] = f2bf(v * sc);
          }
        } else {
          float v = acc[mt][nt][r] + bias[col];
          if constexpr (MODE == M_RES) {      // fp32: attn@Wfc + bfc + x
            size_t idx = (size_t)row * N + col;
            ((float*)outp)[idx] = v + res[idx];
          } else if constexpr (MODE == M_RELU) {
            ((unsigned short*)outp)[(size_t)row * N + col] = f2bf(v > 0.f ? v : 0.f);
          } else {                            // M_F32
            ((float*)outp)[(size_t)row * N + col] = v;
          }
        }
      }
    }
  }
}

// ---------------------------------------------------------------- flash attention
// grid (S/64, B*H); 4 waves x 16 q-rows. KV tiles of 64, double-buffered via
// global_load_lds with pre-swizzled source (linear LDS dest + swizzled read).
// Fixed-shift softmax (p = exp(s-8), shift cancels in p/sum(p)); row sums
// accumulated per-lane, reduced once after the loop. All LDS read addresses
// share the lane-constant swizzle (lr&7)<<4 since row % 8 == lr % 8, so reads
// collapse to base pointers + nt*2048 immediate offsets (address-CSE).
__global__ __launch_bounds__(256, 4)
void flash_attn(const unsigned short* __restrict__ Q,
                const unsigned short* __restrict__ Kb,
                const unsigned short* __restrict__ Vt,
                unsigned short* __restrict__ attnb) {
  const int S = 2048;
  __shared__ unsigned short Qs[64 * 64];          // prologue: Q tile; loop: P buffers
  __shared__ unsigned short Ks[2][64 * 64];
  __shared__ unsigned short Vs[2][64 * 64];
  const int tid = threadIdx.x, l = tid & 63, w = tid >> 6;
  const int lr = l & 15, lg = l >> 4;
  // chunked XCD swizzle: consecutive work items (same head) share an XCD L2
  const int lin = blockIdx.y * gridDim.x + blockIdx.x;   // grid (32, 64), nwg=2048
  const int sw = (lin & 7) * 256 + (lin >> 3);
  const int q0 = (sw & 31) * 64, bh = sw >> 5;
  const unsigned short* Qp = Q + (size_t)bh * S * 64;
  const unsigned short* Kp = Kb + (size_t)bh * S * 64;
  const unsigned short* Vp = Vt + (size_t)bh * 64 * S;

  // Stage one 64x64 bf16 tile. LDS layout after staging == XOR-swizzled:
  // LDS[r*128 + (c2 ^ ((r&7)<<4))] = G[r][c2] (rule 21: linear dest +
  // inverse-swz source + swz read; swizzle permutes 16B chunks in a row).
  auto stage64 = [&](const unsigned short* gbase, size_t rstride, unsigned short* lds) {
#pragma unroll
    for (int i = 0; i < 2; i++) {
      int off16 = i * 256 + tid;        // 16B-chunk index 0..511
      int r = off16 >> 3;               // 8 chunks per 128B row
      int chs = (off16 & 7) ^ (r & 7);  // inverse-swizzled source chunk
      __builtin_amdgcn_global_load_lds(
          (const __attribute__((address_space(1))) unsigned int*)(gbase + (size_t)r * rstride + chs * 8),
          (__attribute__((address_space(3))) unsigned int*)(lds + (size_t)off16 * 8), 16, 0, 0);
    }
  };

  stage64(Qp + (size_t)q0 * 64, 64, Qs);
  stage64(Kp, 64, Ks[0]);
  stage64(Vp, S, Vs[0]);
  __syncthreads();                       // drains vmcnt: tiles ready

  const int swzl = (lr & 7) << 4;        // lane-constant read swizzle
  const int kcol0 = (lg * 16) ^ swzl;    // kk=0 byte col
  const int kcol1 = (64 + lg * 16) ^ swzl;
  const int lr128 = lr * 128;

  short8 qf[2];
  {
    const char* Qb_ = (const char*)Qs + (w * 16 + lr) * 128;
    qf[0] = *(const short8*)(Qb_ + kcol0);
    qf[1] = *(const short8*)(Qb_ + kcol1);
  }
  // Wave w's P region == exactly the Qs bytes only wave w read (rows w*16..w*16+15).
  unsigned short* Pw = Qs + w * 1024;
  char* Pwb = (char*)Pw;
  const int pcol = lr * 2;               // P-write lane byte col (pre-swizzle)

  float lpart[4] = {0.f, 0.f, 0.f, 0.f}; // per-lane partial row sums
  f32x4 oacc[4] = {};

  int cur = 0;
  for (int kv0 = 0; kv0 < S; kv0 += 64) {
    if (kv0 + 64 < S) {                  // prefetch next tile into other buffer
      stage64(Kp + (size_t)(kv0 + 64) * 64, 64, Ks[cur ^ 1]);
      stage64(Vp + (kv0 + 64), S, Vs[cur ^ 1]);
    }
    const char* Kc0 = (const char*)Ks[cur] + lr128 + kcol0;
    const char* Kc1 = (const char*)Ks[cur] + lr128 + kcol1;
    const char* Vc0 = (const char*)Vs[cur] + lr128 + kcol0;
    const char* Vc1 = (const char*)Vs[cur] + lr128 + kcol1;

    f32x4 sa[4] = {};                    // scores: row q=lg*4+r, col kv=nt*16+lr
#pragma unroll
    for (int nt = 0; nt < 4; nt++) {
      sa[nt] = mfma16(qf[0], *(const short8*)(Kc0 + nt * 2048), sa[nt]);
      sa[nt] = mfma16(qf[1], *(const short8*)(Kc1 + nt * 2048), sa[nt]);
    }

    // p = exp(s - 8) = exp2(s*log2e - 11.5416); accumulate per-lane partial l;
    // write truncated bf16 P to per-wave LDS (D-layout write, A-layout read).
#pragma unroll
    for (int r = 0; r < 4; r++) {
      int rr = lg * 4 + r;
      char* baser = Pwb + rr * 128;
      int swzr = (rr & 7) << 4;
#pragma unroll
      for (int nt = 0; nt < 4; nt++) {
        float p = exp2f(fmaf(sa[nt][r], 1.44269504f, -11.5415603f));
        lpart[r] += p;
        *(unsigned short*)(baser + ((nt * 32 + pcol) ^ swzr)) =
            (unsigned short)(__float_as_uint(p) >> 16);   // trunc: P>=0, bias ~2^-9
      }
    }

    short8 pf0, pf1;
    {
      const char* Pb_ = Pwb + lr128;
      pf0 = *(const short8*)(Pb_ + kcol0);
      pf1 = *(const short8*)(Pb_ + kcol1);
    }
#pragma unroll
    for (int nt = 0; nt < 4; nt++) {
      oacc[nt] = mfma16(pf0, *(const short8*)(Vc0 + nt * 2048), oacc[nt]);
      oacc[nt] = mfma16(pf1, *(const short8*)(Vc1 + nt * 2048), oacc[nt]);
    }

    __syncthreads();                     // all waves done with buf[cur]; prefetch drained
    cur ^= 1;
  }

  // one-time row-sum reduce across the 16 lanes of each lane-group
#pragma unroll
  for (int d = 1; d < 16; d <<= 1)
#pragma unroll
    for (int r = 0; r < 4; r++) lpart[r] += __shfl_xor(lpart[r], d, 64);

  const int b = bh >> 4, h = bh & 15;
#pragma unroll
  for (int nt = 0; nt < 4; nt++)
#pragma unroll
    for (int r = 0; r < 4; r++) {
      int s = q0 + w * 16 + lg * 4 + r;
      int col = h * 64 + nt * 16 + lr;
      attnb[(size_t)(b * 2048 + s) * 1024 + col] = f2bf(oacc[nt][r] / lpart[r]);
    }
}

// ---------------------------------------------------------------- layernorm
template <int OUTF32>
__global__ __launch_bounds__(256)
void ln_row(const float* __restrict__ in, const float* __restrict__ g,
            const float* __restrict__ b, void* __restrict__ outp) {
  const int row = blockIdx.x, tid = threadIdx.x;
  float4 v = ((const float4*)(in + (size_t)row * 1024))[tid];
  float s = v.x + v.y + v.z + v.w;
  float s2 = v.x * v.x + v.y * v.y + v.z * v.z + v.w * v.w;
#pragma unroll
  for (int d = 1; d < 64; d <<= 1) { s += __shfl_xor(s, d, 64); s2 += __shfl_xor(s2, d, 64); }
  __shared__ float ps[8];
  if ((tid & 63) == 0) { ps[tid >> 6] = s; ps[4 + (tid >> 6)] = s2; }
  __syncthreads();
  s = ps[0] + ps[1] + ps[2] + ps[3];
  s2 = ps[4] + ps[5] + ps[6] + ps[7];
  float mu = s * (1.f / 1024.f);
  float var = s2 * (1.f / 1024.f) - mu * mu;
  float rstd = rsqrtf(var + 1e-5f);
  float4 gv = ((const float4*)g)[tid];
  float4 bv = ((const float4*)b)[tid];
  float o0 = (v.x - mu) * rstd * gv.x + bv.x;
  float o1 = (v.y - mu) * rstd * gv.y + bv.y;
  float o2 = (v.z - mu) * rstd * gv.z + bv.z;
  float o3 = (v.w - mu) * rstd * gv.w + bv.w;
  if constexpr (OUTF32) {
    float4 o; o.x = o0; o.y = o1; o.z = o2; o.w = o3;
    ((float4*)outp)[(size_t)row * 256 + tid] = o;
  } else {
    ushort4 o; o.x = f2bf(o0); o.y = f2bf(o1); o.z = f2bf(o2); o.w = f2bf(o3);
    ((ushort4*)outp)[(size_t)row * 256 + tid] = o;
  }
}

// ---------------------------------------------------------------- driver
extern "C" void kernel_launch(void* const* d_in, const int* in_sizes, int n_in,
                              void* d_out, int out_size, void* d_ws, size_t ws_size,
                              hipStream_t stream) {
  const float* x   = (const float*)d_in[0];
  const float* Wq  = (const float*)d_in[1];
  const float* bq  = (const float*)d_in[2];
  const float* Wk  = (const float*)d_in[3];
  const float* bk  = (const float*)d_in[4];
  const float* Wv  = (const float*)d_in[5];
  const float* bv  = (const float*)d_in[6];
  const float* Wfc = (const float*)d_in[7];
  const float* bfc = (const float*)d_in[8];
  const float* g1  = (const float*)d_in[9];
  const float* bn1 = (const float*)d_in[10];
  const float* W1  = (const float*)d_in[11];
  const float* b1  = (const float*)d_in[12];
  const float* W2  = (const float*)d_in[13];
  const float* b2  = (const float*)d_in[14];
  const float* g2  = (const float*)d_in[15];
  const float* bn2 = (const float*)d_in[16];

  char* ws = (char*)d_ws;
  size_t off = 0;
  auto alloc = [&](size_t bytes) { size_t o = off; off += (bytes + 255) & ~(size_t)255; return o; };
  unsigned short* xb  = (unsigned short*)(ws + alloc(8192UL * 1024 * 2));
  unsigned short* Wqt = (unsigned short*)(ws + alloc(1024UL * 1024 * 2));   // contiguous with
  unsigned short* Wkt = (unsigned short*)(ws + alloc(1024UL * 1024 * 2));   // Wkt/Wvt: fused
  unsigned short* Wvt = (unsigned short*)(ws + alloc(1024UL * 1024 * 2));   // [3072][1024]
  unsigned short* Wft = (unsigned short*)(ws + alloc(1024UL * 1024 * 2));
  unsigned short* W1t = (unsigned short*)(ws + alloc(4096UL * 1024 * 2));
  unsigned short* W2t = (unsigned short*)(ws + alloc(1024UL * 4096 * 2));
  char* zoneA = ws + alloc(67108864UL);                    // Q,K,Vt,attn | reused: m
  float* y    = (float*)(ws + alloc(33554432UL));          // y | reused: m2
  unsigned short* hb = (unsigned short*)(ws + alloc(16777216UL));

  unsigned short* Qb    = (unsigned short*)zoneA;          // +0, +8388608 (K), +2*8388608 (Vt)
  unsigned short* Kbuf  = Qb + 8388608;
  unsigned short* Vtb   = Kbuf + 8388608;
  unsigned short* attnb = Vtb + 8388608;
  unsigned short* mb    = (unsigned short*)zoneA;
  float* m2 = y;

  dim3 tb(32, 8);
  cvt_bf16<<<8192, 256, 0, stream>>>(x, xb, 2097152);
  cvtT<<<dim3(32, 32), tb, 0, stream>>>(Wq, Wqt, 1024, 1024);
  cvtT<<<dim3(32, 32), tb, 0, stream>>>(Wk, Wkt, 1024, 1024);
  cvtT<<<dim3(32, 32), tb, 0, stream>>>(Wv, Wvt, 1024, 1024);
  cvtT<<<dim3(32, 32), tb, 0, stream>>>(Wfc, Wft, 1024, 1024);
  cvtT<<<dim3(128, 32), tb, 0, stream>>>(W1, W1t, 1024, 4096);
  cvtT<<<dim3(32, 128), tb, 0, stream>>>(W2, W2t, 4096, 1024);

  // fused QKV: Bt = [Wqt; Wkt; Wvt] (contiguous), N=3072, scatter per section
  gemm_bt<M_QKV><<<dim3(64, 24), 256, 0, stream>>>(xb, Wqt, bq, bk, bv, nullptr, Qb, 8192, 3072, 1024);

  flash_attn<<<dim3(32, 64), 256, 0, stream>>>(Qb, Kbuf, Vtb, attnb);

  gemm_bt<M_RES><<<dim3(64, 8), 256, 0, stream>>>(attnb, Wft, bfc, nullptr, nullptr, x, y, 8192, 1024, 1024);
  ln_row<0><<<8192, 256, 0, stream>>>(y, g1, bn1, hb);
  gemm_bt<M_RELU><<<dim3(64, 32), 256, 0, stream>>>(hb, W1t, b1, nullptr, nullptr, nullptr, mb, 8192, 4096, 1024);
  gemm_bt<M_F32><<<dim3(64, 8), 256, 0, stream>>>(mb, W2t, b2, nullptr, nullptr, nullptr, m2, 8192, 1024, 4096);
  ln_row<1><<<8192, 256, 0, stream>>>(m2, g2, bn2, d_out);
}

// Round 8
// 572.179 us; speedup vs baseline: 1.0945x; 1.0945x over previous
//
#include <hip/hip_runtime.h>
#include <hip/hip_bf16.h>

#define DEV __device__ __forceinline__

typedef __attribute__((ext_vector_type(8))) short short8;   // 8 x bf16 (4 VGPRs)
typedef __attribute__((ext_vector_type(4))) float f32x4;

DEV f32x4 mfma16(short8 a, short8 b, f32x4 c) {
  return __builtin_amdgcn_mfma_f32_16x16x32_bf16(a, b, c, 0, 0, 0);
}

DEV unsigned short f2bf(float f) {
  union { float f; unsigned u; } x; x.f = f;
  unsigned r = x.u + 0x7fffu + ((x.u >> 16) & 1u);   // RNE
  return (unsigned short)(r >> 16);
}

// ---------------------------------------------------------------- conversions
__global__ __launch_bounds__(256) void cvt_bf16(const float* __restrict__ in,
                                                unsigned short* __restrict__ out,
                                                int n4) {
  int i = blockIdx.x * 256 + threadIdx.x;
  if (i >= n4) return;
  float4 v = ((const float4*)in)[i];
  ushort4 o;
  o.x = f2bf(v.x); o.y = f2bf(v.y); o.z = f2bf(v.z); o.w = f2bf(v.w);
  ((ushort4*)out)[i] = o;
}

// W [K][N] f32 -> Wt [N][K] bf16  (block (32,8), grid (N/32, K/32))
__global__ __launch_bounds__(256) void cvtT(const float* __restrict__ W,
                                            unsigned short* __restrict__ Wt,
                                            int K, int N) {
  __shared__ float t[32][33];
  int n0 = blockIdx.x * 32, k0 = blockIdx.y * 32;
  int tx = threadIdx.x, ty = threadIdx.y;
#pragma unroll
  for (int i = 0; i < 4; i++)
    t[ty * 4 + i][tx] = W[(size_t)(k0 + ty * 4 + i) * N + n0 + tx];
  __syncthreads();
#pragma unroll
  for (int i = 0; i < 4; i++)
    Wt[(size_t)(n0 + ty * 4 + i) * K + k0 + tx] = f2bf(t[tx][ty * 4 + i]);
}

// ---------------------------------------------------------------- GEMM (m97 structure)
// C[M,N] = A[M,K] (bf16 rm) * Bt[N,K]^T (bf16) + bias, epilogue per MODE.
enum { M_QKV = 0, M_RES = 3, M_RELU = 4, M_F32 = 5 };

template <int MODE>
__global__ __launch_bounds__(256, 2)
void gemm_bt(const unsigned short* __restrict__ A,
             const unsigned short* __restrict__ Bt,
             const float* __restrict__ bias,
             const float* __restrict__ bias2,
             const float* __restrict__ bias3,
             const float* __restrict__ res,
             void* __restrict__ outp, int M, int N, int K) {
  __shared__ unsigned short lA[128 * 64];
  __shared__ unsigned short lB[128 * 64];
  const int tid = threadIdx.x;
  const int l = tid & 63, w = tid >> 6;
  const int wr = w >> 1, wc = w & 1;          // 2x2 wave grid, 64x64 per wave
  const int lr = l & 15, lg = l >> 4;
  const int m0 = blockIdx.x * 128, n0 = blockIdx.y * 128;   // no swizzle (L3-fit regime)
  f32x4 acc[4][4] = {};

  for (int k0 = 0; k0 < K; k0 += 64) {
    __syncthreads();
#pragma unroll
    for (int i = 0; i < 4; i++) {             // A tile 128x64: 4 x 256thr x 16B
      int off = (i * 256 + tid) * 8;
      int r = off >> 6, c = off & 63;
      __builtin_amdgcn_global_load_lds(
          (const __attribute__((address_space(1))) unsigned int*)(A + (size_t)(m0 + r) * K + k0 + c),
          (__attribute__((address_space(3))) unsigned int*)(lA + off), 16, 0, 0);
    }
#pragma unroll
    for (int i = 0; i < 4; i++) {             // B^T tile 128x64
      int off = (i * 256 + tid) * 8;
      int r = off >> 6, c = off & 63;
      __builtin_amdgcn_global_load_lds(
          (const __attribute__((address_space(1))) unsigned int*)(Bt + (size_t)(n0 + r) * K + k0 + c),
          (__attribute__((address_space(3))) unsigned int*)(lB + off), 16, 0, 0);
    }
    __syncthreads();
#pragma unroll
    for (int kk = 0; kk < 2; kk++) {
      short8 af[4], bfr[4];
#pragma unroll
      for (int mt = 0; mt < 4; mt++)
        af[mt] = *(const short8*)(lA + (wr * 64 + mt * 16 + lr) * 64 + kk * 32 + lg * 8);
#pragma unroll
      for (int nt = 0; nt < 4; nt++)
        bfr[nt] = *(const short8*)(lB + (wc * 64 + nt * 16 + lr) * 64 + kk * 32 + lg * 8);
#pragma unroll
      for (int mt = 0; mt < 4; mt++)
#pragma unroll
        for (int nt = 0; nt < 4; nt++)
          acc[mt][nt] = mfma16(af[mt], bfr[nt], acc[mt][nt]);
    }
  }

  // epilogue: C/D layout row=(lane>>4)*4+reg, col=lane&15 (verified m89/m91)
  if constexpr (MODE == M_QKV) {
    // section is block-uniform (128-tile never straddles a 1024 boundary):
    // hoist the branch OUT of the store loops (one uniform jump, 3 bodies).
    const int sect = n0 >> 10;
    unsigned short* o = (unsigned short*)outp;
    if (sect == 2) {                          // Vt[b][h][dh][s]
#pragma unroll
      for (int mt = 0; mt < 4; mt++)
#pragma unroll
        for (int nt = 0; nt < 4; nt++)
#pragma unroll
          for (int r = 0; r < 4; r++) {
            int row = m0 + wr * 64 + mt * 16 + lg * 4 + r;
            int col = n0 + wc * 64 + nt * 16 + lr;
            int c10 = col & 1023;
            float v = acc[mt][nt][r] + bias3[c10];
            int b = row >> 11, s = row & 2047;
            int h = c10 >> 6, dh = c10 & 63;
            o[(size_t)2 * 8388608 + ((size_t)(b * 16 + h) * 64 + dh) * 2048 + s] = f2bf(v);
          }
    } else {                                  // Q (scaled) / K : [b][h][s][dh]
      const float* bp = sect == 0 ? bias : bias2;
      const float sc = sect == 0 ? 0.125f : 1.f;
      const size_t so = (size_t)sect * 8388608;
#pragma unroll
      for (int mt = 0; mt < 4; mt++)
#pragma unroll
        for (int nt = 0; nt < 4; nt++)
#pragma unroll
          for (int r = 0; r < 4; r++) {
            int row = m0 + wr * 64 + mt * 16 + lg * 4 + r;
            int col = n0 + wc * 64 + nt * 16 + lr;
            int c10 = col & 1023;
            float v = (acc[mt][nt][r] + bp[c10]) * sc;
            int b = row >> 11, s = row & 2047;
            int h = c10 >> 6, dh = c10 & 63;
            o[so + (((size_t)(b * 16 + h) * 2048 + s) << 6) + dh] = f2bf(v);
          }
    }
  } else {
#pragma unroll
    for (int mt = 0; mt < 4; mt++)
#pragma unroll
      for (int nt = 0; nt < 4; nt++)
#pragma unroll
        for (int r = 0; r < 4; r++) {
          int row = m0 + wr * 64 + mt * 16 + lg * 4 + r;
          int col = n0 + wc * 64 + nt * 16 + lr;
          float v = acc[mt][nt][r] + bias[col];
          if constexpr (MODE == M_RES) {      // fp32: attn@Wfc + bfc + x
            size_t idx = (size_t)row * N + col;
            ((float*)outp)[idx] = v + res[idx];
          } else if constexpr (MODE == M_RELU) {
            ((unsigned short*)outp)[(size_t)row * N + col] = f2bf(v > 0.f ? v : 0.f);
          } else {                            // M_F32
            ((float*)outp)[(size_t)row * N + col] = v;
          }
        }
  }
}

// ---------------------------------------------------------------- flash attention
// grid (S/128, B*H); 4 waves x 32 q-rows (2 sub-tiles of 16) = 128-row Q block.
// Doubling q-rows/wave halves LDS read bytes per FLOP (K/V reads amortized
// over 2x compute) — flash is LDS-read + VALU bound, not HBM bound (r7:
// FETCH_SIZE 5.7x down, time flat). KV tiles of 64 double-buffered via
// global_load_lds with pre-swizzled source; fixed-shift softmax (exp(s-8),
// shift cancels in p/sum); per-lane partial row sums reduced once at end.
__global__ __launch_bounds__(256, 3)
void flash_attn(const unsigned short* __restrict__ Q,
                const unsigned short* __restrict__ Kb,
                const unsigned short* __restrict__ Vt,
                unsigned short* __restrict__ attnb) {
  const int S = 2048;
  __shared__ unsigned short Qs[128 * 64];         // 16KB; P buffers after qf hoist
  __shared__ unsigned short Ks[2][64 * 64];
  __shared__ unsigned short Vs[2][64 * 64];
  const int tid = threadIdx.x, l = tid & 63, w = tid >> 6;
  const int lr = l & 15, lg = l >> 4;
  // chunked XCD swizzle (kept: FETCH 5.7x lower, time-neutral)
  const int lin = blockIdx.y * gridDim.x + blockIdx.x;   // grid (16,64), nwg=1024
  const int sw = (lin & 7) * 128 + (lin >> 3);
  const int q0 = (sw & 15) * 128, bh = sw >> 4;
  const unsigned short* Qp = Q + (size_t)bh * S * 64;
  const unsigned short* Kp = Kb + (size_t)bh * S * 64;
  const unsigned short* Vp = Vt + (size_t)bh * 64 * S;

  // Stage a 64-col bf16 tile; LDS ends up XOR-swizzled:
  // LDS[r*128 + (c2 ^ ((r&7)<<4))] = G[r][c2] (linear dest + inv-swz source).
  auto stage64 = [&](const unsigned short* gbase, size_t rstride, unsigned short* lds) {
#pragma unroll
    for (int i = 0; i < 2; i++) {
      int off16 = i * 256 + tid;
      int r = off16 >> 3;
      int chs = (off16 & 7) ^ (r & 7);
      __builtin_amdgcn_global_load_lds(
          (const __attribute__((address_space(1))) unsigned int*)(gbase + (size_t)r * rstride + chs * 8),
          (__attribute__((address_space(3))) unsigned int*)(lds + (size_t)off16 * 8), 16, 0, 0);
    }
  };

#pragma unroll
  for (int i = 0; i < 4; i++) {                  // stage Q 128x64 (swizzled)
    int off16 = i * 256 + tid;
    int r = off16 >> 3;
    int chs = (off16 & 7) ^ (r & 7);
    __builtin_amdgcn_global_load_lds(
        (const __attribute__((address_space(1))) unsigned int*)(Qp + (size_t)(q0 + r) * 64 + chs * 8),
        (__attribute__((address_space(3))) unsigned int*)(Qs + (size_t)off16 * 8), 16, 0, 0);
  }
  stage64(Kp, 64, Ks[0]);
  stage64(Vp, S, Vs[0]);
  __syncthreads();                               // tiles ready

  const int swzl = (lr & 7) << 4;                // lane-constant read swizzle
  const int kcol0 = (lg * 16) ^ swzl;
  const int kcol1 = (64 + lg * 16) ^ swzl;
  const int lr128 = lr * 128;

  short8 qf[2][2];
#pragma unroll
  for (int qs = 0; qs < 2; qs++) {
    const char* Qb_ = (const char*)Qs + (w * 32 + qs * 16 + lr) * 128;
    qf[qs][0] = *(const short8*)(Qb_ + kcol0);
    qf[qs][1] = *(const short8*)(Qb_ + kcol1);
  }
  // Wave w's P region = its own (now dead) Q rows: 32 rows x 128B = 4KB.
  char* Pwb = (char*)Qs + w * 4096;
  const int pcol = lr * 2;

  float lpart[2][4] = {};
  f32x4 oacc[2][4] = {};

  int cur = 0;
  for (int kv0 = 0; kv0 < S; kv0 += 64) {
    if (kv0 + 64 < S) {                          // prefetch next tile (other buffer)
      stage64(Kp + (size_t)(kv0 + 64) * 64, 64, Ks[cur ^ 1]);
      stage64(Vp + (kv0 + 64), S, Vs[cur ^ 1]);
    }
    const char* Kc0 = (const char*)Ks[cur] + lr128 + kcol0;
    const char* Kc1 = (const char*)Ks[cur] + lr128 + kcol1;
    const char* Vc0 = (const char*)Vs[cur] + lr128 + kcol0;
    const char* Vc1 = (const char*)Vs[cur] + lr128 + kcol1;

    f32x4 sa[2][4] = {};                         // scores per q-subtile
#pragma unroll
    for (int nt = 0; nt < 4; nt++) {
      short8 k0f = *(const short8*)(Kc0 + nt * 2048);
      short8 k1f = *(const short8*)(Kc1 + nt * 2048);
#pragma unroll
      for (int qs = 0; qs < 2; qs++) {
        sa[qs][nt] = mfma16(qf[qs][0], k0f, sa[qs][nt]);
        sa[qs][nt] = mfma16(qf[qs][1], k1f, sa[qs][nt]);
      }
    }

    // p = exp(s-8) = exp2(s*log2e - 11.5416); per-lane partial sums; P->LDS.
#pragma unroll
    for (int qs = 0; qs < 2; qs++)
#pragma unroll
      for (int r = 0; r < 4; r++) {
        int rr = qs * 16 + lg * 4 + r;
        char* baser = Pwb + rr * 128;
        int swzr = (rr & 7) << 4;
#pragma unroll
        for (int nt = 0; nt < 4; nt++) {
          float p = exp2f(fmaf(sa[qs][nt][r], 1.44269504f, -11.5415603f));
          lpart[qs][r] += p;
          *(unsigned short*)(baser + ((nt * 32 + pcol) ^ swzr)) =
              (unsigned short)(__float_as_uint(p) >> 16);   // trunc: P>=0
        }
      }

    short8 pf[2][2];
#pragma unroll
    for (int qs = 0; qs < 2; qs++) {
      const char* Pb_ = Pwb + qs * 2048 + lr128;
      pf[qs][0] = *(const short8*)(Pb_ + kcol0);
      pf[qs][1] = *(const short8*)(Pb_ + kcol1);
    }
#pragma unroll
    for (int nt = 0; nt < 4; nt++) {
      short8 v0f = *(const short8*)(Vc0 + nt * 2048);
      short8 v1f = *(const short8*)(Vc1 + nt * 2048);
#pragma unroll
      for (int qs = 0; qs < 2; qs++) {
        oacc[qs][nt] = mfma16(pf[qs][0], v0f, oacc[qs][nt]);
        oacc[qs][nt] = mfma16(pf[qs][1], v1f, oacc[qs][nt]);
      }
    }

    __syncthreads();                             // all waves done with buf[cur]
    cur ^= 1;
  }

  // one-time row-sum reduce across the 16 lanes of each lane-group
#pragma unroll
  for (int d = 1; d < 16; d <<= 1)
#pragma unroll
    for (int qs = 0; qs < 2; qs++)
#pragma unroll
      for (int r = 0; r < 4; r++) lpart[qs][r] += __shfl_xor(lpart[qs][r], d, 64);

  const int b = bh >> 4, h = bh & 15;
#pragma unroll
  for (int qs = 0; qs < 2; qs++)
#pragma unroll
    for (int nt = 0; nt < 4; nt++)
#pragma unroll
      for (int r = 0; r < 4; r++) {
        int s = q0 + w * 32 + qs * 16 + lg * 4 + r;
        int col = h * 64 + nt * 16 + lr;
        attnb[(size_t)(b * 2048 + s) * 1024 + col] = f2bf(oacc[qs][nt][r] / lpart[qs][r]);
      }
}

// ---------------------------------------------------------------- layernorm
template <int OUTF32>
__global__ __launch_bounds__(256)
void ln_row(const float* __restrict__ in, const float* __restrict__ g,
            const float* __restrict__ b, void* __restrict__ outp) {
  const int row = blockIdx.x, tid = threadIdx.x;
  float4 v = ((const float4*)(in + (size_t)row * 1024))[tid];
  float s = v.x + v.y + v.z + v.w;
  float s2 = v.x * v.x + v.y * v.y + v.z * v.z + v.w * v.w;
#pragma unroll
  for (int d = 1; d < 64; d <<= 1) { s += __shfl_xor(s, d, 64); s2 += __shfl_xor(s2, d, 64); }
  __shared__ float ps[8];
  if ((tid & 63) == 0) { ps[tid >> 6] = s; ps[4 + (tid >> 6)] = s2; }
  __syncthreads();
  s = ps[0] + ps[1] + ps[2] + ps[3];
  s2 = ps[4] + ps[5] + ps[6] + ps[7];
  float mu = s * (1.f / 1024.f);
  float var = s2 * (1.f / 1024.f) - mu * mu;
  float rstd = rsqrtf(var + 1e-5f);
  float4 gv = ((const float4*)g)[tid];
  float4 bv = ((const float4*)b)[tid];
  float o0 = (v.x - mu) * rstd * gv.x + bv.x;
  float o1 = (v.y - mu) * rstd * gv.y + bv.y;
  float o2 = (v.z - mu) * rstd * gv.z + bv.z;
  float o3 = (v.w - mu) * rstd * gv.w + bv.w;
  if constexpr (OUTF32) {
    float4 o; o.x = o0; o.y = o1; o.z = o2; o.w = o3;
    ((float4*)outp)[(size_t)row * 256 + tid] = o;
  } else {
    ushort4 o; o.x = f2bf(o0); o.y = f2bf(o1); o.z = f2bf(o2); o.w = f2bf(o3);
    ((ushort4*)outp)[(size_t)row * 256 + tid] = o;
  }
}

// ---------------------------------------------------------------- driver
extern "C" void kernel_launch(void* const* d_in, const int* in_sizes, int n_in,
                              void* d_out, int out_size, void* d_ws, size_t ws_size,
                              hipStream_t stream) {
  const float* x   = (const float*)d_in[0];
  const float* Wq  = (const float*)d_in[1];
  const float* bq  = (const float*)d_in[2];
  const float* Wk  = (const float*)d_in[3];
  const float* bk  = (const float*)d_in[4];
  const float* Wv  = (const float*)d_in[5];
  const float* bv  = (const float*)d_in[6];
  const float* Wfc = (const float*)d_in[7];
  const float* bfc = (const float*)d_in[8];
  const float* g1  = (const float*)d_in[9];
  const float* bn1 = (const float*)d_in[10];
  const float* W1  = (const float*)d_in[11];
  const float* b1  = (const float*)d_in[12];
  const float* W2  = (const float*)d_in[13];
  const float* b2  = (const float*)d_in[14];
  const float* g2  = (const float*)d_in[15];
  const float* bn2 = (const float*)d_in[16];

  char* ws = (char*)d_ws;
  size_t off = 0;
  auto alloc = [&](size_t bytes) { size_t o = off; off += (bytes + 255) & ~(size_t)255; return o; };
  unsigned short* xb  = (unsigned short*)(ws + alloc(8192UL * 1024 * 2));
  unsigned short* Wqt = (unsigned short*)(ws + alloc(1024UL * 1024 * 2));   // contiguous with
  unsigned short* Wkt = (unsigned short*)(ws + alloc(1024UL * 1024 * 2));   // Wkt/Wvt: fused
  unsigned short* Wvt = (unsigned short*)(ws + alloc(1024UL * 1024 * 2));   // [3072][1024]
  unsigned short* Wft = (unsigned short*)(ws + alloc(1024UL * 1024 * 2));
  unsigned short* W1t = (unsigned short*)(ws + alloc(4096UL * 1024 * 2));
  unsigned short* W2t = (unsigned short*)(ws + alloc(1024UL * 4096 * 2));
  char* zoneA = ws + alloc(67108864UL);                    // Q,K,Vt,attn | reused: m
  float* y    = (float*)(ws + alloc(33554432UL));          // y | reused: m2
  unsigned short* hb = (unsigned short*)(ws + alloc(16777216UL));

  unsigned short* Qb    = (unsigned short*)zoneA;          // +0, +8388608 (K), +2*8388608 (Vt)
  unsigned short* Kbuf  = Qb + 8388608;
  unsigned short* Vtb   = Kbuf + 8388608;
  unsigned short* attnb = Vtb + 8388608;
  unsigned short* mb    = (unsigned short*)zoneA;
  float* m2 = y;

  dim3 tb(32, 8);
  cvt_bf16<<<8192, 256, 0, stream>>>(x, xb, 2097152);
  cvtT<<<dim3(32, 32), tb, 0, stream>>>(Wq, Wqt, 1024, 1024);
  cvtT<<<dim3(32, 32), tb, 0, stream>>>(Wk, Wkt, 1024, 1024);
  cvtT<<<dim3(32, 32), tb, 0, stream>>>(Wv, Wvt, 1024, 1024);
  cvtT<<<dim3(32, 32), tb, 0, stream>>>(Wfc, Wft, 1024, 1024);
  cvtT<<<dim3(128, 32), tb, 0, stream>>>(W1, W1t, 1024, 4096);
  cvtT<<<dim3(32, 128), tb, 0, stream>>>(W2, W2t, 4096, 1024);

  // fused QKV: Bt = [Wqt; Wkt; Wvt] (contiguous), N=3072, scatter per section
  gemm_bt<M_QKV><<<dim3(64, 24), 256, 0, stream>>>(xb, Wqt, bq, bk, bv, nullptr, Qb, 8192, 3072, 1024);

  flash_attn<<<dim3(16, 64), 256, 0, stream>>>(Qb, Kbuf, Vtb, attnb);

  gemm_bt<M_RES><<<dim3(64, 8), 256, 0, stream>>>(attnb, Wft, bfc, nullptr, nullptr, x, y, 8192, 1024, 1024);
  ln_row<0><<<8192, 256, 0, stream>>>(y, g1, bn1, hb);
  gemm_bt<M_RELU><<<dim3(64, 32), 256, 0, stream>>>(hb, W1t, b1, nullptr, nullptr, nullptr, mb, 8192, 4096, 1024);
  gemm_bt<M_F32><<<dim3(64, 8), 256, 0, stream>>>(mb, W2t, b2, nullptr, nullptr, nullptr, m2, 8192, 1024, 4096);
  ln_row<1><<<8192, 256, 0, stream>>>(m2, g2, bn2, d_out);
}